// Round 2
// baseline (1816.003 us; speedup 1.0000x reference)
//
#include <hip/hip_runtime.h>

#define NUM_CENTERS 256
#define CAPACITY    2048
#define FEAT_DIM    768
#define BATCH       65536
#define VEC_PER_ROW (FEAT_DIM / 4)   // 192 float4 per row (3072 B)

#define THREADS 256                  // 4 waves per block
#define BLOCKS  2048                 // 8192 waves total -> 8 samples per wave

// Native clang vector type: __builtin_nontemporal_store requires it
// (HIP_vector_type float4 is a struct and is rejected).
typedef float f32x4 __attribute__((ext_vector_type(4)));

// One wave (64 lanes) per sample per iteration. Each lane moves 3 float4
// at lane, lane+64, lane+128 -> each wave instruction covers 1 KB contiguous.
// Indices are read via readfirstlane -> scalar (SGPR) row base, fully
// coalesced 16B/lane vector loads. Output is write-once -> nontemporal
// stores to avoid evicting reusable bank rows from L2/L3.
__global__ __launch_bounds__(THREADS, 8) void gather_rows_kernel(
        const f32x4* __restrict__ bank,
        const int*   __restrict__ center_ids,
        const int*   __restrict__ rand_idx,
        f32x4*       __restrict__ out) {
    const int lane   = threadIdx.x & 63;
    const int wave   = (blockIdx.x << 2) | (threadIdx.x >> 6);
    const int nwaves = BLOCKS * (THREADS / 64);   // 8192

#pragma unroll 2
    for (int s = wave; s < BATCH; s += nwaves) {
        // Wave-uniform index loads, forced to SGPR so the row base is scalar.
        const int c = __builtin_amdgcn_readfirstlane(center_ids[s]);
        const int r = __builtin_amdgcn_readfirstlane(rand_idx[s]);

        // 64-bit offsets: bank spans 1.6 GB (402M float4 elements).
        const f32x4* __restrict__ src =
            bank + ((long long)c * CAPACITY + (long long)r) * (long long)VEC_PER_ROW;
        f32x4* __restrict__ dst = out + (long long)s * (long long)VEC_PER_ROW;

        const f32x4 a = src[lane];
        const f32x4 b = src[lane + 64];
        const f32x4 d = src[lane + 128];
        __builtin_nontemporal_store(a, &dst[lane]);
        __builtin_nontemporal_store(b, &dst[lane + 64]);
        __builtin_nontemporal_store(d, &dst[lane + 128]);
    }
}

extern "C" void kernel_launch(void* const* d_in, const int* in_sizes, int n_in,
                              void* d_out, int out_size, void* d_ws, size_t ws_size,
                              hipStream_t stream) {
    const f32x4* bank       = (const f32x4*)d_in[0];
    const int*   center_ids = (const int*)d_in[1];
    const int*   rand_idx   = (const int*)d_in[2];
    f32x4*       out        = (f32x4*)d_out;

    // Problem shape is static (BATCH=65536). Do NOT derive the grid from
    // in_sizes: its unit semantics (bytes vs elements) previously caused a
    // 4x-oversized grid whose OOB writes corrupted neighboring buffers and
    // made graph replays diverge.
    gather_rows_kernel<<<BLOCKS, THREADS, 0, stream>>>(bank, center_ids, rand_idx, out);
}